// Round 10
// baseline (487.289 us; speedup 1.0000x reference)
//
#include <hip/hip_runtime.h>
#include <hip/hip_bf16.h>
#include <math.h>

#define DEVI __device__ __forceinline__

typedef __bf16 bf16x8 __attribute__((ext_vector_type(8)));
typedef float f32x4 __attribute__((ext_vector_type(4)));
typedef unsigned int u32x4 __attribute__((ext_vector_type(4)));
typedef float f32x4v __attribute__((ext_vector_type(4)));
typedef unsigned short u16;

DEVI u16 f2bf(float f) {
    __hip_bfloat16 h = __float2bfloat16(f);
    return __builtin_bit_cast(u16, h);
}
DEVI float bf2f(u16 u) {
    unsigned int x = ((unsigned int)u) << 16;
    return __builtin_bit_cast(float, x);
}
// fast gelu: tanh form via one v_exp; |err| vs exact erf-gelu < ~3e-3 (tolerance is 0.1)
DEVI float gelu_f(float x) {
    float y = 0.7978845608f * (x + 0.044715f * x * x * x);
    float e = __expf(2.f * y);
    float t = 1.f - 2.f / (e + 1.f);
    return 0.5f * x * (1.f + t);
}
DEVI float sigm(float x) { return 1.f / (1.f + __expf(-x)); }

DEVI bf16x8 ldfrag(const u16* p) {
    return __builtin_bit_cast(bf16x8, *reinterpret_cast<const u32x4*>(p));
}

// async global->LDS, 16B/lane; LDS dest = wave-uniform base + lane*16
DEVI void gload_lds16(const u16* g, u16* l) {
    __builtin_amdgcn_global_load_lds(
        (const __attribute__((address_space(1))) void*)g,
        (__attribute__((address_space(3))) void*)l, 16, 0, 0);
}

// Stage 8 rows x 64 u16 (1KB), XOR-chunk swizzle: stored pos p of row r holds
// global chunk p^(r&7) -> ds_read_b128 fragment reads are <=2-way (free).
DEVI void stage8(const u16* gbase, long long stride, u16* lds, int lane) {
    int r = lane >> 3;
    int kg = (lane & 7) ^ r;
    gload_lds16(gbase + (long long)r * stride + kg * 8, lds);
}
// fragment read: row rr (stride-64 tile), logical k-chunk k (0..7)
DEVI bf16x8 fragsw(const u16* tile, int rr, int k) {
    return ldfrag(&tile[rr * 64 + ((k ^ (rr & 7)) << 3)]);
}

// ---------------- transpose + cast fp32 -> bf16 ----------------
__global__ __launch_bounds__(256) void tcast_k(const float* __restrict__ in, u16* __restrict__ out,
                                               int R, int C) {
    __shared__ float tile[32][33];
    int c0 = blockIdx.x * 32, r0 = blockIdx.y * 32;
    for (int ry = threadIdx.y; ry < 32; ry += 8)
        tile[ry][threadIdx.x] = in[(long long)(r0 + ry) * C + c0 + threadIdx.x];
    __syncthreads();
    for (int cy = threadIdx.y; cy < 32; cy += 8)
        out[(long long)(c0 + cy) * R + r0 + threadIdx.x] = f2bf(tile[threadIdx.x][cy]);
}

// ------- layernorm over 768; in = sum of nparts fp32 parts (+bias2) (+in2); x1 optional -------
// zfill: if non-null, blocks <192 also zero zfill[blk*256+tid] (free zero-fill piggyback)
__global__ __launch_bounds__(256) void ln_k(const float* __restrict__ parts, int nparts, long long pstride,
                                            const float* __restrict__ bias2, const float* __restrict__ in2,
                                            const float* __restrict__ w, const float* __restrict__ b,
                                            u16* __restrict__ outbf, float* __restrict__ x1out,
                                            float* __restrict__ zfill) {
    int row = blockIdx.x;
    if (zfill && row < 192) zfill[row * 256 + threadIdx.x] = 0.f;
    long long ro = (long long)row * 768;
    __shared__ float lds1[4], lds2[4];
    float v[3];
    float s = 0.f, sq = 0.f;
#pragma unroll
    for (int j = 0; j < 3; j++) {
        int c = threadIdx.x + j * 256;
        float x = 0.f;
        for (int p = 0; p < nparts; p++) x += parts[p * pstride + ro + c];
        if (bias2) x += bias2[c];
        if (in2) x += in2[ro + c];
        v[j] = x; s += x; sq += x * x;
    }
    if (x1out) {
#pragma unroll
        for (int j = 0; j < 3; j++) x1out[ro + threadIdx.x + j * 256] = v[j];
    }
    for (int off = 32; off; off >>= 1) { s += __shfl_down(s, off); sq += __shfl_down(sq, off); }
    int wid = threadIdx.x >> 6;
    if ((threadIdx.x & 63) == 0) { lds1[wid] = s; lds2[wid] = sq; }
    __syncthreads();
    s = lds1[0] + lds1[1] + lds1[2] + lds1[3];
    sq = lds2[0] + lds2[1] + lds2[2] + lds2[3];
    float mu = s * (1.f / 768.f);
    float var = sq * (1.f / 768.f) - mu * mu;
    float rs = rsqrtf(var + 1e-5f);
#pragma unroll
    for (int j = 0; j < 3; j++) {
        int c = threadIdx.x + j * 256;
        outbf[ro + c] = f2bf((v[j] - mu) * rs * w[c] + b[c]);
    }
}

// ------- 2-wave MFMA GEMM: C = A @ B_t^T, 64x128 tile, BK=64, 24KB LDS, XOR swizzle -------
// Smaller barrier group (2 waves) + more independent blocks/CU (6) than the 4-wave 128x128.
struct GemmP {
    const u16* A; const u16* B;
    float* outF; u16* outB;
    const float* bias;
    u16* qh; u16* kh; u16* vh;
    int K, lda, ldb, ldc;
    long long pstride;
    int epi;     // 0: fp32 part (z*pstride) ; 2: bf16+bias+gelu ; 4: qkv head-split
    int splits;
};

__global__ __launch_bounds__(128) void gemm_bt2(GemmP p) {
    __shared__ u16 As[64 * 64];
    __shared__ u16 Bs[128 * 64];
    const int tid = threadIdx.x, lane = tid & 63, wave = tid >> 6;  // wave in {0,1}
    const int l16 = lane & 15, qd = lane >> 4;
    const int bn0 = blockIdx.x * 128, bm0 = blockIdx.y * 64;
    const int wn0 = wave * 64;
    const int kc = p.K / p.splits;
    const int kbeg = blockIdx.z * kc, kend = kbeg + kc;
    f32x4 acc[4][4] = {};
    for (int k0 = kbeg; k0 < kend; k0 += 64) {
        __syncthreads();  // WAR: prior iter ds_reads done before DMA overwrite
#pragma unroll
        for (int t = 0; t < 4; t++) {
            int rowg = wave * 32 + t * 8;
            stage8(p.A + (long long)(bm0 + rowg) * p.lda + k0, p.lda, As + rowg * 64, lane);
        }
#pragma unroll
        for (int t = 0; t < 8; t++) {
            int rowg = wave * 64 + t * 8;
            stage8(p.B + (long long)(bn0 + rowg) * p.ldb + k0, p.ldb, Bs + rowg * 64, lane);
        }
        __syncthreads();  // drain DMAs
#pragma unroll
        for (int s = 0; s < 2; s++) {
            bf16x8 af[4], bv[4];
#pragma unroll
            for (int i = 0; i < 4; i++) af[i] = fragsw(As, i * 16 + l16, s * 4 + qd);
#pragma unroll
            for (int j = 0; j < 4; j++) bv[j] = fragsw(Bs, wn0 + j * 16 + l16, s * 4 + qd);
#pragma unroll
            for (int i = 0; i < 4; i++)
#pragma unroll
                for (int j = 0; j < 4; j++)
                    acc[i][j] = __builtin_amdgcn_mfma_f32_16x16x32_bf16(af[i], bv[j], acc[i][j], 0, 0, 0);
        }
    }
#pragma unroll
    for (int i = 0; i < 4; i++)
#pragma unroll
        for (int j = 0; j < 4; j++)
#pragma unroll
            for (int r = 0; r < 4; r++) {
                int row = bm0 + i * 16 + qd * 4 + r;
                int col = bn0 + wn0 + j * 16 + l16;
                float v = acc[i][j][r];
                if (p.epi == 0) {
                    p.outF[(long long)blockIdx.z * p.pstride + (long long)row * p.ldc + col] = v;
                } else if (p.epi == 2) {
                    p.outB[(long long)row * p.ldc + col] = f2bf(gelu_f(v + p.bias[col]));
                } else {  // epi 4: qkv head split
                    v += p.bias[col];
                    int sect = col / 768, cc = col % 768;
                    int h = cc >> 6, d = cc & 63;
                    int b = row >> 10, n = row & 1023;
                    long long o = ((long long)(b * 12 + h) * 1024 + n) * 64 + d;
                    if (sect == 0) p.qh[o] = f2bf(v * 0.125f);
                    else if (sect == 1) p.kh[o] = f2bf(v);
                    else p.vh[o] = f2bf(v);
                }
            }
}

// ---------------- gp_w fp32 [12][49][64] -> padded bf16 [12][64][64] ----------------
__global__ __launch_bounds__(256) void gpcast_k(const float* __restrict__ gp_w, u16* __restrict__ gpB) {
    int h = blockIdx.x;
    for (int i = threadIdx.x; i < 4096; i += 256) {
        int m = i >> 6, d = i & 63;
        float v = (m < 49) ? gp_w[h * 3136 + m * 64 + d] : 0.f;
        gpB[h * 4096 + i] = f2bf(v);
    }
}

// ------- MFMA gw0: gwn = softmax(gelu(v @ gp^T)) per head; also zero-fills Wt -------
__global__ __launch_bounds__(256) void gw0m_k(const u16* __restrict__ vh, const u16* __restrict__ gpB,
                                              u16* __restrict__ gwn, float* __restrict__ Wt) {
    // piggyback Wt zero-fill: grid is (16,48)=768 blocks; Wt = 768*256 floats
    {
        long long zi = ((long long)blockIdx.y * 16 + blockIdx.x) * 256 + threadIdx.x;
        Wt[zi] = 0.f;
    }
    __shared__ u16 As[64 * 64];
    __shared__ u16 Bs[64 * 64];
    const int tid = threadIdx.x, lane = tid & 63, wave = tid >> 6;
    const int l16 = lane & 15, qd = lane >> 4;
    const int z = blockIdx.y, n0 = blockIdx.x * 64, h = z % 12;
    const u16* vz = vh + ((long long)z * 1024 + n0) * 64;
    const u16* gz = gpB + h * 4096;
#pragma unroll
    for (int t = 0; t < 2; t++) {
        int rowg = wave * 16 + t * 8;
        stage8(vz + (long long)rowg * 64, 64, As + rowg * 64, lane);
        stage8(gz + (long long)rowg * 64, 64, Bs + rowg * 64, lane);
    }
    __syncthreads();
    f32x4 acc[4] = {};
#pragma unroll
    for (int s = 0; s < 2; s++) {
        bf16x8 af = fragsw(As, wave * 16 + l16, s * 4 + qd);
#pragma unroll
        for (int j = 0; j < 4; j++) {
            bf16x8 bv = fragsw(Bs, j * 16 + l16, s * 4 + qd);
            acc[j] = __builtin_amdgcn_mfma_f32_16x16x32_bf16(af, bv, acc[j], 0, 0, 0);
        }
    }
    float ex[4][4];
#pragma unroll
    for (int r = 0; r < 4; r++) {
        float mx = -1e30f;
        float gv[4];
#pragma unroll
        for (int j = 0; j < 4; j++) {
            int col = j * 16 + l16;
            float g = gelu_f(acc[j][r]);
            gv[j] = g;
            if (col < 49) mx = fmaxf(mx, g);
            else gv[j] = -1e30f;
        }
        mx = fmaxf(mx, __shfl_xor(mx, 1)); mx = fmaxf(mx, __shfl_xor(mx, 2));
        mx = fmaxf(mx, __shfl_xor(mx, 4)); mx = fmaxf(mx, __shfl_xor(mx, 8));
        float s = 0.f;
#pragma unroll
        for (int j = 0; j < 4; j++) {
            int col = j * 16 + l16;
            float e = (col < 49) ? __expf(gv[j] - mx) : 0.f;
            ex[r][j] = e;
            s += e;
        }
        s += __shfl_xor(s, 1); s += __shfl_xor(s, 2);
        s += __shfl_xor(s, 4); s += __shfl_xor(s, 8);
        float inv = 1.f / s;
        int row = wave * 16 + qd * 4 + r;
        long long o = ((long long)z * 1024 + n0 + row) * 64;
#pragma unroll
        for (int j = 0; j < 4; j++)
            gwn[o + j * 16 + l16] = f2bf(ex[r][j] * inv);
    }
}

// ------- 4-wave: e = exp((q@k^T)*(gwn@gwn^T)) bf16 128x128 tile + fp32 rowsum atomics -------
__global__ __launch_bounds__(256) void attn_tg4(const u16* __restrict__ qh, const u16* __restrict__ kh,
                                                const u16* __restrict__ gwn, u16* __restrict__ e,
                                                float* __restrict__ rowsumE) {
    __shared__ u16 As[128 * 64];
    __shared__ u16 Bs[128 * 64];
    const int tid = threadIdx.x, lane = tid & 63, wave = tid >> 6;
    const int l16 = lane & 15, qd = lane >> 4;
    const int bn0 = blockIdx.x * 128, bm0 = blockIdx.y * 128, z = blockIdx.z;
    const int wm0 = (wave >> 1) * 64, wn0 = (wave & 1) * 64;
    const u16* qz = qh + (long long)z * 65536;
    const u16* kz = kh + (long long)z * 65536;
    const u16* gz = gwn + (long long)z * 65536;
    f32x4 accS[4][4] = {};
    f32x4 accG[4][4] = {};
#pragma unroll
    for (int t = 0; t < 4; t++) {
        int rowg = wave * 32 + t * 8;
        stage8(qz + (long long)(bm0 + rowg) * 64, 64, As + rowg * 64, lane);
        stage8(kz + (long long)(bn0 + rowg) * 64, 64, Bs + rowg * 64, lane);
    }
    __syncthreads();
#pragma unroll
    for (int s = 0; s < 2; s++) {
        bf16x8 af[4], bv[4];
#pragma unroll
        for (int i = 0; i < 4; i++) af[i] = fragsw(As, wm0 + i * 16 + l16, s * 4 + qd);
#pragma unroll
        for (int j = 0; j < 4; j++) bv[j] = fragsw(Bs, wn0 + j * 16 + l16, s * 4 + qd);
#pragma unroll
        for (int i = 0; i < 4; i++)
#pragma unroll
            for (int j = 0; j < 4; j++)
                accS[i][j] = __builtin_amdgcn_mfma_f32_16x16x32_bf16(af[i], bv[j], accS[i][j], 0, 0, 0);
    }
    __syncthreads();
#pragma unroll
    for (int t = 0; t < 4; t++) {
        int rowg = wave * 32 + t * 8;
        stage8(gz + (long long)(bm0 + rowg) * 64, 64, As + rowg * 64, lane);
        stage8(gz + (long long)(bn0 + rowg) * 64, 64, Bs + rowg * 64, lane);
    }
    __syncthreads();
#pragma unroll
    for (int s = 0; s < 2; s++) {
        bf16x8 af[4], bv[4];
#pragma unroll
        for (int i = 0; i < 4; i++) af[i] = fragsw(As, wm0 + i * 16 + l16, s * 4 + qd);
#pragma unroll
        for (int j = 0; j < 4; j++) bv[j] = fragsw(Bs, wn0 + j * 16 + l16, s * 4 + qd);
#pragma unroll
        for (int i = 0; i < 4; i++)
#pragma unroll
            for (int j = 0; j < 4; j++)
                accG[i][j] = __builtin_amdgcn_mfma_f32_16x16x32_bf16(af[i], bv[j], accG[i][j], 0, 0, 0);
    }
    long long zoff = (long long)z * 1048576;
#pragma unroll
    for (int i = 0; i < 4; i++)
#pragma unroll
        for (int r = 0; r < 4; r++) {
            int row = bm0 + wm0 + i * 16 + qd * 4 + r;
            float rs = 0.f;
#pragma unroll
            for (int j = 0; j < 4; j++) {
                int col = bn0 + wn0 + j * 16 + l16;
                float ev = __expf(accS[i][j][r] * accG[i][j][r]);  // |t| small, no max-sub
                e[zoff + (long long)row * 1024 + col] = f2bf(ev);
                rs += ev;
            }
            rs += __shfl_xor(rs, 1); rs += __shfl_xor(rs, 2);
            rs += __shfl_xor(rs, 4); rs += __shfl_xor(rs, 8);
            if (l16 == 0) atomicAdd(&rowsumE[z * 1024 + row], rs);
        }
}

// ------- combine2: S[j]=sum_n gwn[n][j]; colsum[m] = a*(gwn[m].S) -------
__global__ __launch_bounds__(256) void combine2_k(const u16* __restrict__ gwn, const float* __restrict__ alpha,
                                                  float* __restrict__ colsum) {
    int z = blockIdx.x, h = z % 12;
    int j = threadIdx.x & 63, part = threadIdx.x >> 6;
    __shared__ float lds[4][64];
    __shared__ float Sl[64];
    float s = 0.f;
    for (int i = 0; i < 256; i++)
        s += bf2f(gwn[((long long)z * 1024 + part * 256 + i) * 64 + j]);
    lds[part][j] = s;
    __syncthreads();
    if (threadIdx.x < 64)
        Sl[threadIdx.x] = lds[0][threadIdx.x] + lds[1][threadIdx.x] + lds[2][threadIdx.x] + lds[3][threadIdx.x];
    __syncthreads();
    float a = sigm(alpha[h]);
    for (int m = threadIdx.x; m < 1024; m += 256) {
        const u16* g = gwn + ((long long)z * 1024 + m) * 64;
        float dot = 0.f;
#pragma unroll 8
        for (int jj = 0; jj < 64; jj++) dot += bf2f(g[jj]) * Sl[jj];
        colsum[z * 1024 + m] = a * dot;
    }
}

// ---- colsum[z][m] += (1-a)*sum_n e[n][m]/rowsum[n]; vectorized dwordx4 (8 cols/load) ----
__global__ __launch_bounds__(256) void colsumE_k(const u16* __restrict__ e, const float* __restrict__ rowsumE,
                                                 const float* __restrict__ alpha, float* __restrict__ colsum) {
    int z = blockIdx.x, h = z % 12;
    int n0 = blockIdx.y * 128;
    int grp = threadIdx.x & 127;       // m-group: cols grp*8 .. grp*8+7
    int half = threadIdx.x >> 7;       // n-subrange of 64
    const u16* p = e + (long long)z * 1048576;
    const float* rs = rowsumE + z * 1024;
    float acc[8] = {};
    for (int n = n0 + half * 64; n < n0 + half * 64 + 64; n++) {
        unsigned int rw[4];
        *reinterpret_cast<u32x4*>(rw) = *reinterpret_cast<const u32x4*>(&p[(long long)n * 1024 + grp * 8]);
        float inv = 1.f / rs[n];
#pragma unroll
        for (int q = 0; q < 4; q++) {
            float lo = __builtin_bit_cast(float, rw[q] << 16);
            float hi = __builtin_bit_cast(float, rw[q] & 0xffff0000u);
            acc[2 * q] += lo * inv;
            acc[2 * q + 1] += hi * inv;
        }
    }
    __shared__ float part[2][128][8];
#pragma unroll
    for (int j = 0; j < 8; j++) part[half][grp][j] = acc[j];
    __syncthreads();
    if (half == 0) {
        float a = sigm(alpha[h]);
#pragma unroll
        for (int j = 0; j < 8; j++)
            atomicAdd(&colsum[z * 1024 + grp * 8 + j], (1.f - a) * (part[0][grp][j] + part[1][grp][j]));
    }
}

// ---------------- v'^T: vpt[z][d][m] = vh[z][m][d] / (colsum+1e-8), bf16 ----------------
__global__ __launch_bounds__(256) void vpt_k(const u16* __restrict__ vh, const float* __restrict__ colsum,
                                             u16* __restrict__ vpt) {
    int z = blockIdx.y, m0 = blockIdx.x * 64;
    __shared__ float ts[64 * 65];
    int mi = threadIdx.x >> 6, d = threadIdx.x & 63;
    for (int rr = 0; rr < 16; rr++) {
        int row = rr * 4 + mi;
        ts[row * 65 + d] = bf2f(vh[((long long)z * 1024 + m0 + row) * 64 + d]);
    }
    __syncthreads();
    int mj = threadIdx.x & 63, d0 = threadIdx.x >> 6;
    for (int rr = 0; rr < 16; rr++) {
        int dd = rr * 4 + d0;
        float cs = colsum[z * 1024 + m0 + mj] + 1e-8f;
        vpt[((long long)z * 64 + dd) * 1024 + m0 + mj] = f2bf(ts[mj * 65 + dd] / cs);
    }
}

// ---------------- Wt[z][d][j] = sum_n gwn[z][n][j] * v'[z][n][d] ----------------
__global__ __launch_bounds__(256) void wgemm_k(const u16* __restrict__ gwn, const u16* __restrict__ vpt,
                                               float* __restrict__ Wt) {
    int z = blockIdx.y, n0 = blockIdx.x * 128;
    __shared__ u16 gs[128 * 64];
    __shared__ u16 vs2[64 * 128];
    for (int i = threadIdx.x; i < 128 * 64; i += 256) {
        int nn = i >> 6, j = i & 63;
        gs[i] = gwn[((long long)z * 1024 + n0 + nn) * 64 + j];
        int d = i >> 7, n2 = i & 127;
        vs2[i] = vpt[((long long)z * 64 + d) * 1024 + n0 + n2];
    }
    __syncthreads();
    int j = threadIdx.x & 63, dg = threadIdx.x >> 6;
    float acc[16] = {};
    for (int nn = 0; nn < 128; nn++) {
        float g = bf2f(gs[nn * 64 + j]);
#pragma unroll
        for (int i = 0; i < 16; i++) acc[i] += g * bf2f(vs2[(dg * 16 + i) * 128 + nn]);
    }
#pragma unroll
    for (int i = 0; i < 16; i++)
        atomicAdd(&Wt[((long long)z * 64 + dg * 16 + i) * 64 + j], acc[i]);
}

// ------- 4-wave: out = (1-a)/rowsum*(e@v') + a*(gwn@Wt^T), BM=64; Wt cast in-kernel -------
__global__ __launch_bounds__(256) void attn_out4(const u16* __restrict__ e, const u16* __restrict__ vpt,
                                                 const u16* __restrict__ gwn, const float* __restrict__ Wt,
                                                 const float* __restrict__ rowsumE,
                                                 const float* __restrict__ alpha, u16* __restrict__ out) {
    __shared__ u16 As[64 * 64];
    __shared__ u16 Bs[64 * 64];
    const int tid = threadIdx.x, lane = tid & 63, wave = tid >> 6;
    const int l16 = lane & 15, qd = lane >> 4;
    const int bm0 = blockIdx.x * 64, z = blockIdx.y;
    const int h = z % 12, b = z / 12;
    const u16* Pz = e + (long long)z * 1048576;
    const u16* vz = vpt + (long long)z * 65536;
    const int wr = wave * 16;
    f32x4 accP[4] = {};
    f32x4 accG[4] = {};
    for (int k0 = 0; k0 < 1024; k0 += 64) {
        __syncthreads();
#pragma unroll
        for (int t = 0; t < 2; t++) {
            int rowg = wave * 16 + t * 8;
            stage8(Pz + (long long)(bm0 + rowg) * 1024 + k0, 1024, As + rowg * 64, lane);
            stage8(vz + (long long)rowg * 1024 + k0, 1024, Bs + rowg * 64, lane);
        }
        __syncthreads();
#pragma unroll
        for (int s = 0; s < 2; s++) {
            bf16x8 af = fragsw(As, wr + l16, s * 4 + qd);
#pragma unroll
            for (int j = 0; j < 4; j++) {
                bf16x8 bv = fragsw(Bs, j * 16 + l16, s * 4 + qd);
                accP[j] = __builtin_amdgcn_mfma_f32_16x16x32_bf16(af, bv, accP[j], 0, 0, 0);
            }
        }
    }
    // G part: gwn rows (bm0..+63) @ Wt^T; Wt fp32 converted to swizzled LDS in-kernel
    const u16* gz = gwn + (long long)z * 65536;
    const float* wz = Wt + (long long)z * 4096;
    __syncthreads();
#pragma unroll
    for (int t = 0; t < 2; t++) {
        int rowg = wave * 16 + t * 8;
        stage8(gz + (long long)(bm0 + rowg) * 64, 64, As + rowg * 64, lane);
    }
    {
        int row = tid >> 2, c0 = (tid & 3) * 16;
        const float* wrow = wz + row * 64;
#pragma unroll
        for (int j0 = 0; j0 < 16; j0++) {
            int j = c0 + j0;
            int pos = (((j >> 3) ^ (row & 7)) << 3) | (j & 7);
            Bs[row * 64 + pos] = f2bf(wrow[j]);
        }
    }
    __syncthreads();
#pragma unroll
    for (int s = 0; s < 2; s++) {
        bf16x8 af = fragsw(As, wr + l16, s * 4 + qd);
#pragma unroll
        for (int j = 0; j < 4; j++) {
            bf16x8 bv = fragsw(Bs, j * 16 + l16, s * 4 + qd);
            accG[j] = __builtin_amdgcn_mfma_f32_16x16x32_bf16(af, bv, accG[j], 0, 0, 0);
        }
    }
    float a = sigm(alpha[h]);
#pragma unroll
    for (int r = 0; r < 4; r++) {
        int n = bm0 + wr + qd * 4 + r;
        float sc = (1.f - a) / rowsumE[z * 1024 + n];
#pragma unroll
        for (int j = 0; j < 4; j++) {
            int d = j * 16 + l16;
            float v = sc * accP[j][r] + a * accG[j][r];
            out[((long long)(b * 1024 + n)) * 768 + h * 64 + d] = f2bf(v);
        }
    }
}

// ------- fuse FF2 parts: d_out = p0+p1 + ff2_b + x1  (float4) -------
__global__ __launch_bounds__(256) void fuse2_k(const float* __restrict__ parts, long long pstride4,
                                               const float* __restrict__ bias, const float* __restrict__ x1,
                                               float* __restrict__ outp) {
    long long i4 = (long long)blockIdx.x * 256 + threadIdx.x;
    int c4 = (int)(i4 % 192);
    const f32x4v* p0 = (const f32x4v*)parts;
    f32x4v v = p0[i4] + p0[pstride4 + i4];
    f32x4v bb = ((const f32x4v*)bias)[c4];
    f32x4v xx = ((const f32x4v*)x1)[i4];
    ((f32x4v*)outp)[i4] = v + bb + xx;
}

// =======================================================================================
extern "C" void kernel_launch(void* const* d_in, const int* in_sizes, int n_in,
                              void* d_out, int out_size, void* d_ws, size_t ws_size,
                              hipStream_t stream) {
    const float* x      = (const float*)d_in[0];
    const float* ln1_w  = (const float*)d_in[1];
    const float* ln1_b  = (const float*)d_in[2];
    const float* qkv_w  = (const float*)d_in[3];
    const float* qkv_b  = (const float*)d_in[4];
    const float* proj_w = (const float*)d_in[5];
    const float* proj_b = (const float*)d_in[6];
    const float* gp_w   = (const float*)d_in[7];
    const float* alpha  = (const float*)d_in[8];
    const float* ln2_w  = (const float*)d_in[9];
    const float* ln2_b  = (const float*)d_in[10];
    const float* ff1_w  = (const float*)d_in[11];
    const float* ff1_b  = (const float*)d_in[12];
    const float* ff2_w  = (const float*)d_in[13];
    const float* ff2_b  = (const float*)d_in[14];

    char* w = (char*)d_ws;
    size_t off = 0;
    auto alloc = [&](size_t bytes) { size_t r = off; off += (bytes + 255) & ~(size_t)255; return r; };

    u16*   xn_bf   = (u16*)(w + alloc(4096LL * 768 * 2));
    u16*   wqkv_t  = (u16*)(w + alloc(2304LL * 768 * 2));
    u16*   wproj_t = (u16*)(w + alloc(768LL * 768 * 2));
    u16*   wff1_t  = (u16*)(w + alloc(3072LL * 768 * 2));
    u16*   wff2_t  = (u16*)(w + alloc(768LL * 3072 * 2));
    u16*   gpB     = (u16*)(w + alloc(12LL * 64 * 64 * 2));
    u16*   qh      = (u16*)(w + alloc(48LL * 1024 * 64 * 2));
    u16*   kh      = (u16*)(w + alloc(48LL * 1024 * 64 * 2));
    u16*   vh      = (u16*)(w + alloc(48LL * 1024 * 64 * 2));
    u16*   gwn     = (u16*)(w + alloc(48LL * 1024 * 64 * 2));
    u16*   ebuf    = (u16*)(w + alloc(48LL * 1024 * 1024 * 2));  // e; later proj parts / hmid / ff2 parts
    float* rowsumE = (float*)(w + alloc(48LL * 1024 * 4));
    float* Wt      = (float*)(w + alloc(48LL * 64 * 64 * 4));
    float* colsum  = (float*)(w + alloc(48LL * 1024 * 4));
    u16*   vpt     = (u16*)(w + alloc(48LL * 64 * 1024 * 2));
    float* x1      = (float*)(w + alloc(4096LL * 768 * 4));
    u16*   attn_o  = (u16*)(w + alloc(4096LL * 768 * 2));
    u16*   xn2     = (u16*)(w + alloc(4096LL * 768 * 2));
    float* projP = (float*)ebuf;
    u16*   hmid  = (u16*)((char*)ebuf + 2 * 4096LL * 768 * 4);
    float* ff2P  = (float*)((char*)ebuf + 2 * 4096LL * 768 * 4 + 4096LL * 3072 * 2);

    dim3 blk(256);
    dim3 blk2(128);
    const long long PS = 4096LL * 768;

    // weight transpose-casts + gp pad-cast
    tcast_k<<<dim3(72, 24), dim3(32, 8), 0, stream>>>(qkv_w, wqkv_t, 768, 2304);
    tcast_k<<<dim3(24, 24), dim3(32, 8), 0, stream>>>(proj_w, wproj_t, 768, 768);
    tcast_k<<<dim3(96, 24), dim3(32, 8), 0, stream>>>(ff1_w, wff1_t, 768, 3072);
    tcast_k<<<dim3(24, 96), dim3(32, 8), 0, stream>>>(ff2_w, wff2_t, 3072, 768);
    gpcast_k<<<dim3(12), blk, 0, stream>>>(gp_w, gpB);

    // LN1 (+ rowsumE zero-fill piggyback)
    ln_k<<<dim3(4096), blk, 0, stream>>>(x, 1, 0, nullptr, nullptr, ln1_w, ln1_b, xn_bf, nullptr, rowsumE);

    // QKV GEMM -> qh/kh/vh directly (2-wave, 64x128)
    {
        GemmP p = {xn_bf, wqkv_t, nullptr, nullptr, qkv_b, qh, kh, vh, 768, 768, 768, 0, 0, 4, 1};
        gemm_bt2<<<dim3(18, 64, 1), blk2, 0, stream>>>(p);
    }

    // group weights (MFMA) + Wt zero-fill piggyback
    gw0m_k<<<dim3(16, 48), blk, 0, stream>>>(vh, gpB, gwn, Wt);

    // e = exp((q@k^T)*(gwn@gwn^T)) + exact rowsums
    attn_tg4<<<dim3(8, 8, 48), blk, 0, stream>>>(qh, kh, gwn, ebuf, rowsumE);

    // colsum = a*(gwn.S) ; += (1-a)*sum_n e/rowsum
    combine2_k<<<dim3(48), blk, 0, stream>>>(gwn, alpha, colsum);
    colsumE_k<<<dim3(48, 8), blk, 0, stream>>>(ebuf, rowsumE, alpha, colsum);

    // v'^T
    vpt_k<<<dim3(16, 48), blk, 0, stream>>>(vh, colsum, vpt);

    // Wt = (gwn^T @ v')^T  (atomic into pre-zeroed Wt)
    wgemm_k<<<dim3(8, 48), blk, 0, stream>>>(gwn, vpt, Wt);

    // attention output (head-merged bf16), 4-wave BM=64, Wt cast in-kernel
    attn_out4<<<dim3(16, 48), blk, 0, stream>>>(ebuf, vpt, gwn, Wt, rowsumE, alpha, attn_o);

    // proj GEMM -> 2 fp32 parts (2-wave; e dead)
    {
        GemmP p = {attn_o, wproj_t, projP, nullptr, nullptr, nullptr, nullptr, nullptr,
                   768, 768, 768, 768, PS, 0, 2};
        gemm_bt2<<<dim3(6, 64, 2), blk2, 0, stream>>>(p);
    }

    // x1 = proj0+proj1+proj_b + x ; LN2 -> xn2
    ln_k<<<dim3(4096), blk, 0, stream>>>(projP, 2, PS, proj_b, x, ln2_w, ln2_b, xn2, x1, nullptr);

    // FF1 + gelu -> hmid bf16 (2-wave)
    {
        GemmP p = {xn2, wff1_t, nullptr, hmid, ff1_b, nullptr, nullptr, nullptr,
                   768, 768, 768, 3072, 0, 2, 1};
        gemm_bt2<<<dim3(24, 64, 1), blk2, 0, stream>>>(p);
    }

    // FF2 -> 2 fp32 parts (2-wave)
    {
        GemmP p = {hmid, wff2_t, ff2P, nullptr, nullptr, nullptr, nullptr, nullptr,
                   3072, 3072, 3072, 768, PS, 0, 2};
        gemm_bt2<<<dim3(6, 64, 2), blk2, 0, stream>>>(p);
    }

    // d_out = p0+p1 + ff2_b + x1
    fuse2_k<<<dim3(3072), blk, 0, stream>>>(ff2P, PS / 4, ff2_b, x1, (float*)d_out);
}

// Round 11
// 465.953 us; speedup vs baseline: 1.0458x; 1.0458x over previous
//
#include <hip/hip_runtime.h>
#include <hip/hip_bf16.h>
#include <math.h>

#define DEVI __device__ __forceinline__

typedef __bf16 bf16x8 __attribute__((ext_vector_type(8)));
typedef float f32x4 __attribute__((ext_vector_type(4)));
typedef float f32x2 __attribute__((ext_vector_type(2)));
typedef unsigned int u32x4 __attribute__((ext_vector_type(4)));
typedef float f32x4v __attribute__((ext_vector_type(4)));
typedef unsigned short u16;
typedef unsigned char u8;

DEVI u16 f2bf(float f) {
    __hip_bfloat16 h = __float2bfloat16(f);
    return __builtin_bit_cast(u16, h);
}
DEVI float bf2f(u16 u) {
    unsigned int x = ((unsigned int)u) << 16;
    return __builtin_bit_cast(float, x);
}
// fast gelu: tanh form via one v_exp; |err| vs exact erf-gelu < ~3e-3 (tolerance is 0.1)
DEVI float gelu_f(float x) {
    float y = 0.7978845608f * (x + 0.044715f * x * x * x);
    float e = __expf(2.f * y);
    float t = 1.f - 2.f / (e + 1.f);
    return 0.5f * x * (1.f + t);
}
DEVI float sigm(float x) { return 1.f / (1.f + __expf(-x)); }

DEVI bf16x8 ldfrag(const u16* p) {
    return __builtin_bit_cast(bf16x8, *reinterpret_cast<const u32x4*>(p));
}

// async global->LDS, 16B/lane; LDS dest = wave-uniform base + lane*16
DEVI void gload_lds16(const u16* g, u16* l) {
    __builtin_amdgcn_global_load_lds(
        (const __attribute__((address_space(1))) void*)g,
        (__attribute__((address_space(3))) void*)l, 16, 0, 0);
}

// Stage 8 rows x 64 u16 (1KB), XOR-chunk swizzle: stored pos p of row r holds
// global chunk p^(r&7) -> ds_read_b128 fragment reads are <=2-way (free).
DEVI void stage8(const u16* gbase, long long stride, u16* lds, int lane) {
    int r = lane >> 3;
    int kg = (lane & 7) ^ r;
    gload_lds16(gbase + (long long)r * stride + kg * 8, lds);
}
// fragment read: row rr (stride-64 tile), logical k-chunk k (0..7)
DEVI bf16x8 fragsw(const u16* tile, int rr, int k) {
    return ldfrag(&tile[rr * 64 + ((k ^ (rr & 7)) << 3)]);
}

// pack two f32 into bf16x2 (exact when values came from fp8)
DEVI unsigned int packbf(float a, float b) {
    return __builtin_amdgcn_perm(__builtin_bit_cast(unsigned int, b),
                                 __builtin_bit_cast(unsigned int, a), 0x07060302u);
}

// ---------------- merged weight transpose-casts + gp pad-cast ----------------
__global__ __launch_bounds__(256) void tcast_all(const float* __restrict__ qkv_w, const float* __restrict__ proj_w,
                                                 const float* __restrict__ ff1_w, const float* __restrict__ ff2_w,
                                                 const float* __restrict__ gp_w,
                                                 u16* __restrict__ wqkv, u16* __restrict__ wproj,
                                                 u16* __restrict__ wff1, u16* __restrict__ wff2,
                                                 u16* __restrict__ gpB) {
    int id = blockIdx.x;
    if (id >= 6912) {  // gp pad-cast: [12][49][64] fp32 -> [12][64][64] bf16
        int h = id - 6912;
        int tid = threadIdx.y * 32 + threadIdx.x;
        for (int i = tid; i < 4096; i += 256) {
            int m = i >> 6, d = i & 63;
            float v = (m < 49) ? gp_w[h * 3136 + m * 64 + d] : 0.f;
            gpB[h * 4096 + i] = f2bf(v);
        }
        return;
    }
    const float* in; u16* out; int R, C, tx;
    if (id < 1728)      { in = qkv_w;  out = wqkv;  R = 768;  C = 2304; tx = 72; }
    else if (id < 2304) { in = proj_w; out = wproj; R = 768;  C = 768;  tx = 24; id -= 1728; }
    else if (id < 4608) { in = ff1_w;  out = wff1;  R = 768;  C = 3072; tx = 96; id -= 2304; }
    else                { in = ff2_w;  out = wff2;  R = 3072; C = 768;  tx = 24; id -= 4608; }
    int c0 = (id % tx) * 32, r0 = (id / tx) * 32;
    __shared__ float tile[32][33];
    for (int ry = threadIdx.y; ry < 32; ry += 8)
        tile[ry][threadIdx.x] = in[(long long)(r0 + ry) * C + c0 + threadIdx.x];
    __syncthreads();
    for (int cy = threadIdx.y; cy < 32; cy += 8)
        out[(long long)(c0 + cy) * R + r0 + threadIdx.x] = f2bf(tile[threadIdx.x][cy]);
}

// ------- layernorm over 768; in = sum of nparts fp32 parts (+bias2) (+in2); x1 optional -------
// zfill: if non-null, blocks <192 also zero zfill[blk*256+tid]
__global__ __launch_bounds__(256) void ln_k(const float* __restrict__ parts, int nparts, long long pstride,
                                            const float* __restrict__ bias2, const float* __restrict__ in2,
                                            const float* __restrict__ w, const float* __restrict__ b,
                                            u16* __restrict__ outbf, float* __restrict__ x1out,
                                            float* __restrict__ zfill) {
    int row = blockIdx.x;
    if (zfill && row < 192) zfill[row * 256 + threadIdx.x] = 0.f;
    long long ro = (long long)row * 768;
    __shared__ float lds1[4], lds2[4];
    float v[3];
    float s = 0.f, sq = 0.f;
#pragma unroll
    for (int j = 0; j < 3; j++) {
        int c = threadIdx.x + j * 256;
        float x = 0.f;
        for (int p = 0; p < nparts; p++) x += parts[p * pstride + ro + c];
        if (bias2) x += bias2[c];
        if (in2) x += in2[ro + c];
        v[j] = x; s += x; sq += x * x;
    }
    if (x1out) {
#pragma unroll
        for (int j = 0; j < 3; j++) x1out[ro + threadIdx.x + j * 256] = v[j];
    }
    for (int off = 32; off; off >>= 1) { s += __shfl_down(s, off); sq += __shfl_down(sq, off); }
    int wid = threadIdx.x >> 6;
    if ((threadIdx.x & 63) == 0) { lds1[wid] = s; lds2[wid] = sq; }
    __syncthreads();
    s = lds1[0] + lds1[1] + lds1[2] + lds1[3];
    sq = lds2[0] + lds2[1] + lds2[2] + lds2[3];
    float mu = s * (1.f / 768.f);
    float var = sq * (1.f / 768.f) - mu * mu;
    float rs = rsqrtf(var + 1e-5f);
#pragma unroll
    for (int j = 0; j < 3; j++) {
        int c = threadIdx.x + j * 256;
        outbf[ro + c] = f2bf((v[j] - mu) * rs * w[c] + b[c]);
    }
}

// ------- 4-wave MFMA GEMM: C = A @ B_t^T, 128x128 tile, BK=64, 32KB LDS, XOR swizzle -------
struct GemmP {
    const u16* A; const u16* B;
    float* outF; u16* outB;
    const float* bias;
    u16* qh; u16* kh; u16* vh;
    int K, lda, ldb, ldc;
    long long pstride;
    int epi;     // 0: fp32 part (z*pstride) ; 2: bf16+bias+gelu ; 4: qkv head-split
    int splits;
};

__global__ __launch_bounds__(256) void gemm_bt4(GemmP p) {
    __shared__ u16 As[128 * 64];
    __shared__ u16 Bs[128 * 64];
    const int tid = threadIdx.x, lane = tid & 63, wave = tid >> 6;
    const int l16 = lane & 15, qd = lane >> 4;
    const int bn0 = blockIdx.x * 128, bm0 = blockIdx.y * 128;
    const int wm0 = (wave >> 1) * 64, wn0 = (wave & 1) * 64;
    const int kc = p.K / p.splits;
    const int kbeg = blockIdx.z * kc, kend = kbeg + kc;
    f32x4 acc[4][4] = {};
    for (int k0 = kbeg; k0 < kend; k0 += 64) {
        __syncthreads();
#pragma unroll
        for (int t = 0; t < 4; t++) {
            int rowg = wave * 32 + t * 8;
            stage8(p.A + (long long)(bm0 + rowg) * p.lda + k0, p.lda, As + rowg * 64, lane);
            stage8(p.B + (long long)(bn0 + rowg) * p.ldb + k0, p.ldb, Bs + rowg * 64, lane);
        }
        __syncthreads();
#pragma unroll
        for (int s = 0; s < 2; s++) {
            bf16x8 af[4], bv[4];
#pragma unroll
            for (int i = 0; i < 4; i++) af[i] = fragsw(As, wm0 + i * 16 + l16, s * 4 + qd);
#pragma unroll
            for (int j = 0; j < 4; j++) bv[j] = fragsw(Bs, wn0 + j * 16 + l16, s * 4 + qd);
#pragma unroll
            for (int i = 0; i < 4; i++)
#pragma unroll
                for (int j = 0; j < 4; j++)
                    acc[i][j] = __builtin_amdgcn_mfma_f32_16x16x32_bf16(af[i], bv[j], acc[i][j], 0, 0, 0);
        }
    }
#pragma unroll
    for (int i = 0; i < 4; i++)
#pragma unroll
        for (int j = 0; j < 4; j++)
#pragma unroll
            for (int r = 0; r < 4; r++) {
                int row = bm0 + wm0 + i * 16 + qd * 4 + r;
                int col = bn0 + wn0 + j * 16 + l16;
                float v = acc[i][j][r];
                if (p.epi == 0) {
                    p.outF[(long long)blockIdx.z * p.pstride + (long long)row * p.ldc + col] = v;
                } else if (p.epi == 2) {
                    p.outB[(long long)row * p.ldc + col] = f2bf(gelu_f(v + p.bias[col]));
                } else {  // epi 4: qkv head split
                    v += p.bias[col];
                    int sect = col / 768, cc = col % 768;
                    int h = cc >> 6, d = cc & 63;
                    int b = row >> 10, n = row & 1023;
                    long long o = ((long long)(b * 12 + h) * 1024 + n) * 64 + d;
                    if (sect == 0) p.qh[o] = f2bf(v * 0.125f);
                    else if (sect == 1) p.kh[o] = f2bf(v);
                    else p.vh[o] = f2bf(v);
                }
            }
}

// ------- MFMA gw0: gwn = softmax(gelu(v @ gp^T)) per head; also zero-fills Wt -------
__global__ __launch_bounds__(256) void gw0m_k(const u16* __restrict__ vh, const u16* __restrict__ gpB,
                                              u16* __restrict__ gwn, float* __restrict__ Wt) {
    {
        long long zi = ((long long)blockIdx.y * 16 + blockIdx.x) * 256 + threadIdx.x;
        Wt[zi] = 0.f;
    }
    __shared__ u16 As[64 * 64];
    __shared__ u16 Bs[64 * 64];
    const int tid = threadIdx.x, lane = tid & 63, wave = tid >> 6;
    const int l16 = lane & 15, qd = lane >> 4;
    const int z = blockIdx.y, n0 = blockIdx.x * 64, h = z % 12;
    const u16* vz = vh + ((long long)z * 1024 + n0) * 64;
    const u16* gz = gpB + h * 4096;
#pragma unroll
    for (int t = 0; t < 2; t++) {
        int rowg = wave * 16 + t * 8;
        stage8(vz + (long long)rowg * 64, 64, As + rowg * 64, lane);
        stage8(gz + (long long)rowg * 64, 64, Bs + rowg * 64, lane);
    }
    __syncthreads();
    f32x4 acc[4] = {};
#pragma unroll
    for (int s = 0; s < 2; s++) {
        bf16x8 af = fragsw(As, wave * 16 + l16, s * 4 + qd);
#pragma unroll
        for (int j = 0; j < 4; j++) {
            bf16x8 bv = fragsw(Bs, j * 16 + l16, s * 4 + qd);
            acc[j] = __builtin_amdgcn_mfma_f32_16x16x32_bf16(af, bv, acc[j], 0, 0, 0);
        }
    }
    float ex[4][4];
#pragma unroll
    for (int r = 0; r < 4; r++) {
        float mx = -1e30f;
        float gv[4];
#pragma unroll
        for (int j = 0; j < 4; j++) {
            int col = j * 16 + l16;
            float g = gelu_f(acc[j][r]);
            gv[j] = g;
            if (col < 49) mx = fmaxf(mx, g);
            else gv[j] = -1e30f;
        }
        mx = fmaxf(mx, __shfl_xor(mx, 1)); mx = fmaxf(mx, __shfl_xor(mx, 2));
        mx = fmaxf(mx, __shfl_xor(mx, 4)); mx = fmaxf(mx, __shfl_xor(mx, 8));
        float s = 0.f;
#pragma unroll
        for (int j = 0; j < 4; j++) {
            int col = j * 16 + l16;
            float e = (col < 49) ? __expf(gv[j] - mx) : 0.f;
            ex[r][j] = e;
            s += e;
        }
        s += __shfl_xor(s, 1); s += __shfl_xor(s, 2);
        s += __shfl_xor(s, 4); s += __shfl_xor(s, 8);
        float inv = 1.f / s;
        int row = wave * 16 + qd * 4 + r;
        long long o = ((long long)z * 1024 + n0 + row) * 64;
#pragma unroll
        for (int j = 0; j < 4; j++)
            gwn[o + j * 16 + l16] = f2bf(ex[r][j] * inv);
    }
}

// ------- 4-wave: e = exp((q@k^T)*(gwn@gwn^T)) -> FP8 e4m3, + fp32 rowsum atomics -------
__global__ __launch_bounds__(256) void attn_tg4(const u16* __restrict__ qh, const u16* __restrict__ kh,
                                                const u16* __restrict__ gwn, u8* __restrict__ e8,
                                                float* __restrict__ rowsumE) {
    __shared__ u16 As[128 * 64];
    __shared__ u16 Bs[128 * 64];
    const int tid = threadIdx.x, lane = tid & 63, wave = tid >> 6;
    const int l16 = lane & 15, qd = lane >> 4;
    const int bn0 = blockIdx.x * 128, bm0 = blockIdx.y * 128, z = blockIdx.z;
    const int wm0 = (wave >> 1) * 64, wn0 = (wave & 1) * 64;
    const u16* qz = qh + (long long)z * 65536;
    const u16* kz = kh + (long long)z * 65536;
    const u16* gz = gwn + (long long)z * 65536;
    f32x4 accS[4][4] = {};
    f32x4 accG[4][4] = {};
#pragma unroll
    for (int t = 0; t < 4; t++) {
        int rowg = wave * 32 + t * 8;
        stage8(qz + (long long)(bm0 + rowg) * 64, 64, As + rowg * 64, lane);
        stage8(kz + (long long)(bn0 + rowg) * 64, 64, Bs + rowg * 64, lane);
    }
    __syncthreads();
#pragma unroll
    for (int s = 0; s < 2; s++) {
        bf16x8 af[4], bv[4];
#pragma unroll
        for (int i = 0; i < 4; i++) af[i] = fragsw(As, wm0 + i * 16 + l16, s * 4 + qd);
#pragma unroll
        for (int j = 0; j < 4; j++) bv[j] = fragsw(Bs, wn0 + j * 16 + l16, s * 4 + qd);
#pragma unroll
        for (int i = 0; i < 4; i++)
#pragma unroll
            for (int j = 0; j < 4; j++)
                accS[i][j] = __builtin_amdgcn_mfma_f32_16x16x32_bf16(af[i], bv[j], accS[i][j], 0, 0, 0);
    }
    __syncthreads();
#pragma unroll
    for (int t = 0; t < 4; t++) {
        int rowg = wave * 32 + t * 8;
        stage8(gz + (long long)(bm0 + rowg) * 64, 64, As + rowg * 64, lane);
        stage8(gz + (long long)(bn0 + rowg) * 64, 64, Bs + rowg * 64, lane);
    }
    __syncthreads();
#pragma unroll
    for (int s = 0; s < 2; s++) {
        bf16x8 af[4], bv[4];
#pragma unroll
        for (int i = 0; i < 4; i++) af[i] = fragsw(As, wm0 + i * 16 + l16, s * 4 + qd);
#pragma unroll
        for (int j = 0; j < 4; j++) bv[j] = fragsw(Bs, wn0 + j * 16 + l16, s * 4 + qd);
#pragma unroll
        for (int i = 0; i < 4; i++)
#pragma unroll
            for (int j = 0; j < 4; j++)
                accG[i][j] = __builtin_amdgcn_mfma_f32_16x16x32_bf16(af[i], bv[j], accG[i][j], 0, 0, 0);
    }
    long long zoff = (long long)z * 1048576;
#pragma unroll
    for (int i = 0; i < 4; i++)
#pragma unroll
        for (int r = 0; r < 4; r++) {
            int row = bm0 + wm0 + i * 16 + qd * 4 + r;
            float rs = 0.f;
#pragma unroll
            for (int j = 0; j < 4; j++) {
                int col = bn0 + wn0 + j * 16 + l16;
                float ev = __expf(accS[i][j][r] * accG[i][j][r]);  // |t| small, no max-sub
                unsigned int pk = (unsigned int)__builtin_amdgcn_cvt_pk_fp8_f32(ev, ev, 0, false);
                e8[zoff + (long long)row * 1024 + col] = (u8)(pk & 0xff);
                rs += ev;
            }
            rs += __shfl_xor(rs, 1); rs += __shfl_xor(rs, 2);
            rs += __shfl_xor(rs, 4); rs += __shfl_xor(rs, 8);
            if (l16 == 0) atomicAdd(&rowsumE[z * 1024 + row], rs);
        }
}

// ------- combine2: S[j]=sum_n gwn[n][j]; colsum[m] = a*(gwn[m].S) -------
__global__ __launch_bounds__(256) void combine2_k(const u16* __restrict__ gwn, const float* __restrict__ alpha,
                                                  float* __restrict__ colsum) {
    int z = blockIdx.x, h = z % 12;
    int j = threadIdx.x & 63, part = threadIdx.x >> 6;
    __shared__ float lds[4][64];
    __shared__ float Sl[64];
    float s = 0.f;
    for (int i = 0; i < 256; i++)
        s += bf2f(gwn[((long long)z * 1024 + part * 256 + i) * 64 + j]);
    lds[part][j] = s;
    __syncthreads();
    if (threadIdx.x < 64)
        Sl[threadIdx.x] = lds[0][threadIdx.x] + lds[1][threadIdx.x] + lds[2][threadIdx.x] + lds[3][threadIdx.x];
    __syncthreads();
    float a = sigm(alpha[h]);
    for (int m = threadIdx.x; m < 1024; m += 256) {
        const u16* g = gwn + ((long long)z * 1024 + m) * 64;
        float dot = 0.f;
#pragma unroll 8
        for (int jj = 0; jj < 64; jj++) dot += bf2f(g[jj]) * Sl[jj];
        colsum[z * 1024 + m] = a * dot;
    }
}

// ---- colsum[z][m] += (1-a)*sum_n e8[n][m]/rowsum[n]; fp8 dwordx2 loads (8 cols) ----
__global__ __launch_bounds__(256) void colsumE_k(const u8* __restrict__ e8, const float* __restrict__ rowsumE,
                                                 const float* __restrict__ alpha, float* __restrict__ colsum) {
    int z = blockIdx.x, h = z % 12;
    int n0 = blockIdx.y * 128;
    int grp = threadIdx.x & 127;       // col group: cols grp*8 .. grp*8+7
    int half = threadIdx.x >> 7;       // n-subrange of 64
    const u8* p = e8 + (long long)z * 1048576;
    const float* rs = rowsumE + z * 1024;
    float acc[8] = {};
    for (int n = n0 + half * 64; n < n0 + half * 64 + 64; n++) {
        unsigned long long w8 = *reinterpret_cast<const unsigned long long*>(&p[(long long)n * 1024 + grp * 8]);
        unsigned int w0 = (unsigned int)w8, w1 = (unsigned int)(w8 >> 32);
        float inv = 1.f / rs[n];
        f32x2 a0 = __builtin_amdgcn_cvt_pk_f32_fp8((int)w0, false);
        f32x2 a1 = __builtin_amdgcn_cvt_pk_f32_fp8((int)w0, true);
        f32x2 a2 = __builtin_amdgcn_cvt_pk_f32_fp8((int)w1, false);
        f32x2 a3 = __builtin_amdgcn_cvt_pk_f32_fp8((int)w1, true);
        acc[0] += a0.x * inv; acc[1] += a0.y * inv;
        acc[2] += a1.x * inv; acc[3] += a1.y * inv;
        acc[4] += a2.x * inv; acc[5] += a2.y * inv;
        acc[6] += a3.x * inv; acc[7] += a3.y * inv;
    }
    __shared__ float part[2][128][8];
#pragma unroll
    for (int j = 0; j < 8; j++) part[half][grp][j] = acc[j];
    __syncthreads();
    if (half == 0) {
        float a = sigm(alpha[h]);
#pragma unroll
        for (int j = 0; j < 8; j++)
            atomicAdd(&colsum[z * 1024 + grp * 8 + j], (1.f - a) * (part[0][grp][j] + part[1][grp][j]));
    }
}

// ---------------- v'^T: vpt[z][d][m] = vh[z][m][d] / (colsum+1e-8), bf16 ----------------
__global__ __launch_bounds__(256) void vpt_k(const u16* __restrict__ vh, const float* __restrict__ colsum,
                                             u16* __restrict__ vpt) {
    int z = blockIdx.y, m0 = blockIdx.x * 64;
    __shared__ float ts[64 * 65];
    int mi = threadIdx.x >> 6, d = threadIdx.x & 63;
    for (int rr = 0; rr < 16; rr++) {
        int row = rr * 4 + mi;
        ts[row * 65 + d] = bf2f(vh[((long long)z * 1024 + m0 + row) * 64 + d]);
    }
    __syncthreads();
    int mj = threadIdx.x & 63, d0 = threadIdx.x >> 6;
    for (int rr = 0; rr < 16; rr++) {
        int dd = rr * 4 + d0;
        float cs = colsum[z * 1024 + m0 + mj] + 1e-8f;
        vpt[((long long)z * 64 + dd) * 1024 + m0 + mj] = f2bf(ts[mj * 65 + dd] / cs);
    }
}

// ---------------- Wt[z][d][j] = sum_n gwn[z][n][j] * v'[z][n][d] ----------------
__global__ __launch_bounds__(256) void wgemm_k(const u16* __restrict__ gwn, const u16* __restrict__ vpt,
                                               float* __restrict__ Wt) {
    int z = blockIdx.y, n0 = blockIdx.x * 128;
    __shared__ u16 gs[128 * 64];
    __shared__ u16 vs2[64 * 128];
    for (int i = threadIdx.x; i < 128 * 64; i += 256) {
        int nn = i >> 6, j = i & 63;
        gs[i] = gwn[((long long)z * 1024 + n0 + nn) * 64 + j];
        int d = i >> 7, n2 = i & 127;
        vs2[i] = vpt[((long long)z * 64 + d) * 1024 + n0 + n2];
    }
    __syncthreads();
    int j = threadIdx.x & 63, dg = threadIdx.x >> 6;
    float acc[16] = {};
    for (int nn = 0; nn < 128; nn++) {
        float g = bf2f(gs[nn * 64 + j]);
#pragma unroll
        for (int i = 0; i < 16; i++) acc[i] += g * bf2f(vs2[(dg * 16 + i) * 128 + nn]);
    }
#pragma unroll
    for (int i = 0; i < 16; i++)
        atomicAdd(&Wt[((long long)z * 64 + dg * 16 + i) * 64 + j], acc[i]);
}

// ------- 4-wave: out = (1-a)/rowsum*(e@v') + a*(gwn@Wt^T), BM=64; e fp8, Wt cast in-kernel -------
__global__ __launch_bounds__(256) void attn_out4(const u8* __restrict__ e8, const u16* __restrict__ vpt,
                                                 const u16* __restrict__ gwn, const float* __restrict__ Wt,
                                                 const float* __restrict__ rowsumE,
                                                 const float* __restrict__ alpha, u16* __restrict__ out) {
    __shared__ u16 As[64 * 64];
    __shared__ u16 Bs[64 * 64];
    const int tid = threadIdx.x, lane = tid & 63, wave = tid >> 6;
    const int l16 = lane & 15, qd = lane >> 4;
    const int bm0 = blockIdx.x * 64, z = blockIdx.y;
    const int h = z % 12, b = z / 12;
    const u8* Pz = e8 + (long long)z * 1048576;
    const u16* vz = vpt + (long long)z * 65536;
    const int wr = wave * 16;
    f32x4 accP[4] = {};
    f32x4 accG[4] = {};
    // A-stage lane mapping: row = wr + (lane>>2), chunk-pair cp = (lane&3)*2
    const int arow = wr + (lane >> 2);
    const int cp = (lane & 3) * 2;
    for (int k0 = 0; k0 < 1024; k0 += 64) {
        __syncthreads();
        // A tile: fp8 global load -> exact bf16 convert -> swizzled LDS
        {
            u32x4 wv = *reinterpret_cast<const u32x4*>(Pz + (long long)(bm0 + arow) * 1024 + k0 + cp * 8);
            unsigned int ob[8];
#pragma unroll
            for (int k = 0; k < 4; k++) {
                f32x2 lo = __builtin_amdgcn_cvt_pk_f32_fp8((int)wv[k], false);
                f32x2 hi = __builtin_amdgcn_cvt_pk_f32_fp8((int)wv[k], true);
                ob[2 * k]     = packbf(lo.x, lo.y);
                ob[2 * k + 1] = packbf(hi.x, hi.y);
            }
            int p0 = (cp ^ (arow & 7)) << 3;
            int p1 = ((cp + 1) ^ (arow & 7)) << 3;
            *reinterpret_cast<u32x4*>(&As[arow * 64 + p0]) = *reinterpret_cast<u32x4*>(&ob[0]);
            *reinterpret_cast<u32x4*>(&As[arow * 64 + p1]) = *reinterpret_cast<u32x4*>(&ob[4]);
        }
        // B tile: vpt rows 0..63 (d), DMA
#pragma unroll
        for (int t = 0; t < 2; t++) {
            int rowg = wave * 16 + t * 8;
            stage8(vz + (long long)rowg * 1024 + k0, 1024, Bs + rowg * 64, lane);
        }
        __syncthreads();
#pragma unroll
        for (int s = 0; s < 2; s++) {
            bf16x8 af = fragsw(As, wr + l16, s * 4 + qd);
#pragma unroll
            for (int j = 0; j < 4; j++) {
                bf16x8 bv = fragsw(Bs, j * 16 + l16, s * 4 + qd);
                accP[j] = __builtin_amdgcn_mfma_f32_16x16x32_bf16(af, bv, accP[j], 0, 0, 0);
            }
        }
    }
    // G part: gwn rows (bm0..+63) @ Wt^T; Wt fp32 converted to swizzled LDS in-kernel
    const u16* gz = gwn + (long long)z * 65536;
    const float* wz = Wt + (long long)z * 4096;
    __syncthreads();
#pragma unroll
    for (int t = 0; t < 2; t++) {
        int rowg = wave * 16 + t * 8;
        stage8(gz + (long long)(bm0 + rowg) * 64, 64, As + rowg * 64, lane);
    }
    {
        int row = tid >> 2, c0 = (tid & 3) * 16;
        const float* wrow = wz + row * 64;
#pragma unroll
        for (int j0 = 0; j0 < 16; j0++) {
            int j = c0 + j0;
            int pos = (((j >> 3) ^ (row & 7)) << 3) | (j & 7);
            Bs[row * 64 + pos] = f2bf(wrow[j]);
        }
    }
    __syncthreads();
#pragma unroll
    for (int s = 0; s < 2; s++) {
        bf16x8 af = fragsw(As, wr + l16, s * 4 + qd);
#pragma unroll
        for (int j = 0; j < 4; j++) {
            bf16x8 bv = fragsw(Bs, j * 16 + l16, s * 4 + qd);
            accG[j] = __builtin_amdgcn_mfma_f32_16x16x32_bf16(af, bv, accG[j], 0, 0, 0);
        }
    }
    float a = sigm(alpha[h]);
#pragma unroll
    for (int r = 0; r < 4; r++) {
        int n = bm0 + wr + qd * 4 + r;
        float sc = (1.f - a) / rowsumE[z * 1024 + n];
#pragma unroll
        for (int j = 0; j < 4; j++) {
            int d = j * 16 + l16;
            float v = sc * accP[j][r] + a * accG[j][r];
            out[((long long)(b * 1024 + n)) * 768 + h * 64 + d] = f2bf(v);
        }
    }
}

// ------- fuse FF2 parts: d_out = p0+p1 + ff2_b + x1  (float4) -------
__global__ __launch_bounds__(256) void fuse2_k(const float* __restrict__ parts, long long pstride4,
                                               const float* __restrict__ bias, const float* __restrict__ x1,
                                               float* __restrict__ outp) {
    long long i4 = (long long)blockIdx.x * 256 + threadIdx.x;
    int c4 = (int)(i4 % 192);
    const f32x4v* p0 = (const f32x4v*)parts;
    f32x4v v = p0[i4] + p0[pstride4 + i4];
    f32x4v bb = ((const f32x4v*)bias)[c4];
    f32x4v xx = ((const f32x4v*)x1)[i4];
    ((f32x4v*)outp)[i4] = v + bb + xx;
}

// =======================================================================================
extern "C" void kernel_launch(void* const* d_in, const int* in_sizes, int n_in,
                              void* d_out, int out_size, void* d_ws, size_t ws_size,
                              hipStream_t stream) {
    const float* x      = (const float*)d_in[0];
    const float* ln1_w  = (const float*)d_in[1];
    const float* ln1_b  = (const float*)d_in[2];
    const float* qkv_w  = (const float*)d_in[3];
    const float* qkv_b  = (const float*)d_in[4];
    const float* proj_w = (const float*)d_in[5];
    const float* proj_b = (const float*)d_in[6];
    const float* gp_w   = (const float*)d_in[7];
    const float* alpha  = (const float*)d_in[8];
    const float* ln2_w  = (const float*)d_in[9];
    const float* ln2_b  = (const float*)d_in[10];
    const float* ff1_w  = (const float*)d_in[11];
    const float* ff1_b  = (const float*)d_in[12];
    const float* ff2_w  = (const float*)d_in[13];
    const float* ff2_b  = (const float*)d_in[14];

    char* w = (char*)d_ws;
    size_t off = 0;
    auto alloc = [&](size_t bytes) { size_t r = off; off += (bytes + 255) & ~(size_t)255; return r; };

    u16*   xn_bf   = (u16*)(w + alloc(4096LL * 768 * 2));
    u16*   wqkv_t  = (u16*)(w + alloc(2304LL * 768 * 2));
    u16*   wproj_t = (u16*)(w + alloc(768LL * 768 * 2));
    u16*   wff1_t  = (u16*)(w + alloc(3072LL * 768 * 2));
    u16*   wff2_t  = (u16*)(w + alloc(768LL * 3072 * 2));
    u16*   gpB     = (u16*)(w + alloc(12LL * 64 * 64 * 2));
    u16*   qh      = (u16*)(w + alloc(48LL * 1024 * 64 * 2));
    u16*   kh      = (u16*)(w + alloc(48LL * 1024 * 64 * 2));
    u16*   vh      = (u16*)(w + alloc(48LL * 1024 * 64 * 2));
    u16*   gwn     = (u16*)(w + alloc(48LL * 1024 * 64 * 2));
    // ebuf region sized for max(e8 48MB, proj parts 25MB + hmid 25MB + ff2 parts 25MB = 75.5MB)
    char*  ebase   = w + alloc(2 * 4096LL * 768 * 4 + 4096LL * 3072 * 2 + 2 * 4096LL * 768 * 4);
    u8*    e8      = (u8*)ebase;
    float* rowsumE = (float*)(w + alloc(48LL * 1024 * 4));
    float* Wt      = (float*)(w + alloc(48LL * 64 * 64 * 4));
    float* colsum  = (float*)(w + alloc(48LL * 1024 * 4));
    u16*   vpt     = (u16*)(w + alloc(48LL * 64 * 1024 * 2));
    float* x1      = (float*)(w + alloc(4096LL * 768 * 4));
    u16*   attn_o  = (u16*)(w + alloc(4096LL * 768 * 2));
    u16*   xn2     = (u16*)(w + alloc(4096LL * 768 * 2));
    float* projP = (float*)ebase;
    u16*   hmid  = (u16*)(ebase + 2 * 4096LL * 768 * 4);
    float* ff2P  = (float*)(ebase + 2 * 4096LL * 768 * 4 + 4096LL * 3072 * 2);

    dim3 blk(256);
    const long long PS = 4096LL * 768;

    // merged weight transpose-casts + gp pad-cast (1 launch)
    tcast_all<<<dim3(6924), dim3(32, 8), 0, stream>>>(qkv_w, proj_w, ff1_w, ff2_w, gp_w,
                                                      wqkv_t, wproj_t, wff1_t, wff2_t, gpB);

    // LN1 (+ rowsumE zero-fill piggyback)
    ln_k<<<dim3(4096), blk, 0, stream>>>(x, 1, 0, nullptr, nullptr, ln1_w, ln1_b, xn_bf, nullptr, rowsumE);

    // QKV GEMM -> qh/kh/vh directly
    {
        GemmP p = {xn_bf, wqkv_t, nullptr, nullptr, qkv_b, qh, kh, vh, 768, 768, 768, 0, 0, 4, 1};
        gemm_bt4<<<dim3(18, 32, 1), blk, 0, stream>>>(p);
    }

    // group weights (MFMA) + Wt zero-fill piggyback
    gw0m_k<<<dim3(16, 48), blk, 0, stream>>>(vh, gpB, gwn, Wt);

    // e (fp8) = exp((q@k^T)*(gwn@gwn^T)) + exact rowsums
    attn_tg4<<<dim3(8, 8, 48), blk, 0, stream>>>(qh, kh, gwn, e8, rowsumE);

    // colsum = a*(gwn.S) ; += (1-a)*sum_n e/rowsum
    combine2_k<<<dim3(48), blk, 0, stream>>>(gwn, alpha, colsum);
    colsumE_k<<<dim3(48, 8), blk, 0, stream>>>(e8, rowsumE, alpha, colsum);

    // v'^T
    vpt_k<<<dim3(16, 48), blk, 0, stream>>>(vh, colsum, vpt);

    // Wt = (gwn^T @ v')^T  (atomic into pre-zeroed Wt)
    wgemm_k<<<dim3(8, 48), blk, 0, stream>>>(gwn, vpt, Wt);

    // attention output (head-merged bf16), 4-wave BM=64, fp8 A-tile + Wt cast in-kernel
    attn_out4<<<dim3(16, 48), blk, 0, stream>>>(e8, vpt, gwn, Wt, rowsumE, alpha, attn_o);

    // proj GEMM -> 2 fp32 parts (no atomics; e dead)
    {
        GemmP p = {attn_o, wproj_t, projP, nullptr, nullptr, nullptr, nullptr, nullptr,
                   768, 768, 768, 768, PS, 0, 2};
        gemm_bt4<<<dim3(6, 32, 2), blk, 0, stream>>>(p);
    }

    // x1 = proj0+proj1+proj_b + x ; LN2 -> xn2
    ln_k<<<dim3(4096), blk, 0, stream>>>(projP, 2, PS, proj_b, x, ln2_w, ln2_b, xn2, x1, nullptr);

    // FF1 + gelu -> hmid bf16
    {
        GemmP p = {xn2, wff1_t, nullptr, hmid, ff1_b, nullptr, nullptr, nullptr,
                   768, 768, 768, 3072, 0, 2, 1};
        gemm_bt4<<<dim3(24, 32, 1), blk, 0, stream>>>(p);
    }

    // FF2 -> 2 fp32 parts (no atomics)
    {
        GemmP p = {hmid, wff2_t, ff2P, nullptr, nullptr, nullptr, nullptr, nullptr,
                   3072, 3072, 3072, 768, PS, 0, 2};
        gemm_bt4<<<dim3(6, 32, 2), blk, 0, stream>>>(p);
    }

    // d_out = p0+p1 + ff2_b + x1
    fuse2_k<<<dim3(3072), blk, 0, stream>>>(ff2P, PS / 4, ff2_b, x1, (float*)d_out);
}